// Round 1
// baseline (2500.588 us; speedup 1.0000x reference)
//
#include <hip/hip_runtime.h>
#include <algorithm>

#define FIN 24
#define NHID 64
#define NMIX 216
#define NOUT 6
#define BN_EPS 1e-5f

// degree by dst
__global__ void k_deg(const int* __restrict__ ei, int E, float* deg) {
    int e = blockIdx.x * blockDim.x + threadIdx.x;
    if (e < E) atomicAdd(&deg[ei[E + e]], 1.0f);
}

// deg -> 1/sqrt(deg) (0 if deg==0), in place
__global__ void k_dis(float* d, int n) {
    int i = blockIdx.x * blockDim.x + threadIdx.x;
    if (i < n) { float v = d[i]; d[i] = v > 0.f ? rsqrtf(v) : 0.f; }
}

// per-edge norm = -(dis[src]*dis[dst])
__global__ void k_norm(const int* __restrict__ ei, int E, const float* __restrict__ dis,
                       float* __restrict__ nrm) {
    int e = blockIdx.x * blockDim.x + threadIdx.x;
    if (e < E) nrm[e] = -dis[ei[e]] * dis[ei[E + e]];
}

// out[dst,f] += h[src,f] * norm[e]; thread per (edge,feat)
__global__ void k_prop(const int* __restrict__ ei, int E, const float* __restrict__ nrm,
                       const float* __restrict__ h, float* out) {
    int idx = blockIdx.x * blockDim.x + threadIdx.x;
    if (idx >= E * FIN) return;
    int e = idx / FIN, f = idx - e * FIN;
    int s = ei[e], d = ei[E + e];
    atomicAdd(&out[d * FIN + f], h[s * FIN + f] * nrm[e]);
}

// mode 0: acc = b + S@W
// mode 1: acc += S@W
// mode 2: t = 2*S - prev; Swr = t; (opt) prevwr = 0; acc += t@W
__global__ void k_gemv(const float* __restrict__ S, const float* __restrict__ prev,
                       float* __restrict__ Swr, float* __restrict__ prevwr,
                       float* __restrict__ acc, const float* __restrict__ W,
                       const float* __restrict__ b, int n, int mode, int zero_prev) {
    __shared__ float Ws[FIN * NHID];
    for (int i = threadIdx.x; i < FIN * NHID; i += blockDim.x) Ws[i] = W[i];
    __syncthreads();
    int nn = blockIdx.x * blockDim.x + threadIdx.x;
    if (nn >= n) return;
    float t[FIN];
#pragma unroll
    for (int f = 0; f < FIN; ++f) t[f] = S[nn * FIN + f];
    if (mode == 2) {
#pragma unroll
        for (int f = 0; f < FIN; ++f) {
            t[f] = 2.f * t[f] - prev[nn * FIN + f];
            Swr[nn * FIN + f] = t[f];
        }
        if (zero_prev) {
#pragma unroll
            for (int f = 0; f < FIN; ++f) prevwr[nn * FIN + f] = 0.f;
        }
    }
    for (int j = 0; j < NHID; ++j) {
        float a = (mode == 0) ? b[j] : acc[nn * NHID + j];
#pragma unroll
        for (int f = 0; f < FIN; ++f) a = fmaf(t[f], Ws[f * NHID + j], a);
        acc[nn * NHID + j] = a;
    }
}

// per-feature sum & sumsq -> stats[0:64], stats[64:128]
__global__ void k_bnstats(const float* __restrict__ acc, int n, float* stats) {
    __shared__ float ssum[NHID], ssq[NHID];
    if (threadIdx.x < NHID) { ssum[threadIdx.x] = 0.f; ssq[threadIdx.x] = 0.f; }
    __syncthreads();
    int f = threadIdx.x & 63, rg = threadIdx.x >> 6;  // 256 threads -> 4 row groups
    float s = 0.f, q = 0.f;
    for (int r = blockIdx.x * 4 + rg; r < n; r += gridDim.x * 4) {
        float v = acc[r * NHID + f];
        s += v;
        q = fmaf(v, v, q);
    }
    atomicAdd(&ssum[f], s);
    atomicAdd(&ssq[f], q);
    __syncthreads();
    if (threadIdx.x < NHID) {
        atomicAdd(&stats[threadIdx.x], ssum[threadIdx.x]);
        atomicAdd(&stats[NHID + threadIdx.x], ssq[threadIdx.x]);
    }
}

// in-place BN (biased var) + ReLU
__global__ void k_bnrelu(float* acc, int n, const float* __restrict__ stats,
                         const float* __restrict__ g, const float* __restrict__ bt) {
    int idx = blockIdx.x * blockDim.x + threadIdx.x;
    if (idx >= n * NHID) return;
    int f = idx & 63;
    float inv_n = 1.0f / (float)n;
    float m = stats[f] * inv_n;
    float v = stats[NHID + f] * inv_n - m * m;
    float sc = g[f] * rsqrtf(v + BN_EPS);
    float sh = fmaf(-m, sc, bt[f]);
    acc[idx] = fmaxf(fmaf(acc[idx], sc, sh), 0.f);
}

// segment-mean scatter: xp[cl[n],f] += x[n,f]; cnt[cl[n]] += 1 (f==0 lane)
__global__ void k_scatter(const float* __restrict__ x, const int* __restrict__ cl,
                          int n, float* xp, float* cnt) {
    int idx = blockIdx.x * blockDim.x + threadIdx.x;
    if (idx >= n * FIN) return;
    int node = idx / FIN, f = idx - node * FIN;
    int c = cl[node];
    atomicAdd(&xp[c * FIN + f], x[idx]);
    if (f == 0) atomicAdd(&cnt[c], 1.f);
}

__global__ void k_divcnt(float* xp, const float* __restrict__ cnt, int c) {
    int idx = blockIdx.x * blockDim.x + threadIdx.x;
    if (idx >= c * FIN) return;
    xp[idx] = xp[idx] / fmaxf(cnt[idx / FIN], 1.f);
}

// fused: BN1+ReLU on acc1, gather h2[c1], h3[c2], concat with x, @Wm + bm
__global__ void k_final(const float* __restrict__ acc1, const float* __restrict__ stats1,
                        const float* __restrict__ g1, const float* __restrict__ bt1,
                        const float* __restrict__ h2, const int* __restrict__ cl1,
                        const float* __restrict__ h3, const int* __restrict__ cl2,
                        const float* __restrict__ x, const float* __restrict__ Wm,
                        const float* __restrict__ bm, float* __restrict__ out, int n) {
    __shared__ float Wms[NMIX * NOUT];
    __shared__ float sc1[NHID], sh1[NHID];
    for (int i = threadIdx.x; i < NMIX * NOUT; i += blockDim.x) Wms[i] = Wm[i];
    if (threadIdx.x < NHID) {
        float inv_n = 1.0f / (float)n;
        float m = stats1[threadIdx.x] * inv_n;
        float v = stats1[NHID + threadIdx.x] * inv_n - m * m;
        float s = g1[threadIdx.x] * rsqrtf(v + BN_EPS);
        sc1[threadIdx.x] = s;
        sh1[threadIdx.x] = fmaf(-m, s, bt1[threadIdx.x]);
    }
    __syncthreads();
    int nn = blockIdx.x * blockDim.x + threadIdx.x;
    if (nn >= n) return;
    float o[NOUT];
#pragma unroll
    for (int j = 0; j < NOUT; ++j) o[j] = bm[j];
    int c1 = cl1[nn], c2 = cl2[nn];
    for (int i = 0; i < NHID; ++i) {
        float h = fmaxf(fmaf(acc1[nn * NHID + i], sc1[i], sh1[i]), 0.f);
#pragma unroll
        for (int j = 0; j < NOUT; ++j) o[j] = fmaf(h, Wms[i * NOUT + j], o[j]);
    }
    for (int i = 0; i < NHID; ++i) {
        float h = h2[c1 * NHID + i];
#pragma unroll
        for (int j = 0; j < NOUT; ++j) o[j] = fmaf(h, Wms[(64 + i) * NOUT + j], o[j]);
    }
    for (int i = 0; i < NHID; ++i) {
        float h = h3[c2 * NHID + i];
#pragma unroll
        for (int j = 0; j < NOUT; ++j) o[j] = fmaf(h, Wms[(128 + i) * NOUT + j], o[j]);
    }
    for (int i = 0; i < FIN; ++i) {
        float h = x[nn * FIN + i];
#pragma unroll
        for (int j = 0; j < NOUT; ++j) o[j] = fmaf(h, Wms[(192 + i) * NOUT + j], o[j]);
    }
#pragma unroll
    for (int j = 0; j < NOUT; ++j) out[nn * NOUT + j] = o[j];
}

extern "C" void kernel_launch(void* const* d_in, const int* in_sizes, int n_in,
                              void* d_out, int out_size, void* d_ws, size_t ws_size,
                              hipStream_t stream) {
    const int N = 200000, E = 800000;
    const int C1n = 20000, E1 = 80000;
    const int C2n = 2000, E2 = 8000;

    const float* x  = (const float*)d_in[0];
    const int* ei   = (const int*)d_in[1];
    const int* cl1  = (const int*)d_in[2];
    const int* cl2  = (const int*)d_in[3];
    const int* eic1 = (const int*)d_in[4];
    const int* eic2 = (const int*)d_in[5];
    const float* W1 = (const float*)d_in[6];  const float* b1 = (const float*)d_in[7];
    const float* g1 = (const float*)d_in[8];  const float* bt1 = (const float*)d_in[9];
    const float* W2 = (const float*)d_in[10]; const float* b2 = (const float*)d_in[11];
    const float* g2 = (const float*)d_in[12]; const float* bt2 = (const float*)d_in[13];
    const float* W3 = (const float*)d_in[14]; const float* b3 = (const float*)d_in[15];
    const float* g3 = (const float*)d_in[16]; const float* bt3 = (const float*)d_in[17];
    const float* Wm = (const float*)d_in[18]; const float* bm = (const float*)d_in[19];

    float* w = (float*)d_ws;
    size_t off = 0;
    auto alloc = [&](size_t nf) { float* p = w + off; off += nf; return p; };
    // --- zero-region (atomic accumulators / rotating prop targets) ---
    float* B1[3]; for (int i = 0; i < 3; ++i) B1[i] = alloc((size_t)N * FIN);
    float* B2[3]; for (int i = 0; i < 3; ++i) B2[i] = alloc((size_t)C1n * FIN);
    float* B3[3]; for (int i = 0; i < 3; ++i) B3[i] = alloc((size_t)C2n * FIN);
    float* dis1 = alloc(N); float* dis2 = alloc(C1n); float* dis3 = alloc(C2n);
    float* st1 = alloc(128); float* st2 = alloc(128); float* st3 = alloc(128);
    float* xp1 = alloc((size_t)C1n * FIN); float* cnt1 = alloc(C1n);
    float* xp2 = alloc((size_t)C2n * FIN); float* cnt2 = alloc(C2n);
    size_t zero_floats = off;
    // --- fully-overwritten region ---
    float* acc1 = alloc((size_t)N * NHID);
    float* acc2 = alloc((size_t)C1n * NHID);
    float* acc3 = alloc((size_t)C2n * NHID);
    float* nrm1 = alloc(E); float* nrm2 = alloc(E1); float* nrm3 = alloc(E2);
    if (off * sizeof(float) > ws_size) return;  // workspace too small: fail visibly

    hipMemsetAsync(d_ws, 0, zero_floats * sizeof(float), stream);

    const int T = 256;
    auto cdiv = [](int a, int b) { return (a + b - 1) / b; };

    auto branch = [&](const float* xin, int n, const int* e, int Ecnt,
                      const float* W, const float* bb, float* dis, float* nrm,
                      float** B, float* acc, float* st) {
        int ge = cdiv(Ecnt, T), gn = cdiv(n, T), gp = cdiv(Ecnt * FIN, T);
        k_deg<<<ge, T, 0, stream>>>(e, Ecnt, dis);
        k_dis<<<gn, T, 0, stream>>>(dis, n);
        k_norm<<<ge, T, 0, stream>>>(e, Ecnt, dis, nrm);
        // k=0: acc = b + x@W0
        k_gemv<<<gn, T, 0, stream>>>(xin, nullptr, nullptr, nullptr, acc, W, bb, n, 0, 0);
        // k=1: Tx1 = prop(x) -> B0
        k_prop<<<gp, T, 0, stream>>>(e, Ecnt, nrm, xin, B[0]);
        k_gemv<<<gn, T, 0, stream>>>(B[0], nullptr, nullptr, nullptr, acc, W + 1 * FIN * NHID, bb, n, 1, 0);
        // k=2: Tx2 = 2*prop(B0) - x -> B1
        k_prop<<<gp, T, 0, stream>>>(e, Ecnt, nrm, B[0], B[1]);
        k_gemv<<<gn, T, 0, stream>>>(B[1], xin, B[1], nullptr, acc, W + 2 * FIN * NHID, bb, n, 2, 0);
        // k=3: Tx3 = 2*prop(B1) - B0 -> B2 ; zero B0 (next prop target)
        k_prop<<<gp, T, 0, stream>>>(e, Ecnt, nrm, B[1], B[2]);
        k_gemv<<<gn, T, 0, stream>>>(B[2], B[0], B[2], B[0], acc, W + 3 * FIN * NHID, bb, n, 2, 1);
        // k=4: Tx4 = 2*prop(B2) - B1 -> B0 ; zero B1
        k_prop<<<gp, T, 0, stream>>>(e, Ecnt, nrm, B[2], B[0]);
        k_gemv<<<gn, T, 0, stream>>>(B[0], B[1], B[0], B[1], acc, W + 4 * FIN * NHID, bb, n, 2, 1);
        // k=5: Tx5 = 2*prop(B0) - B2 -> B1
        k_prop<<<gp, T, 0, stream>>>(e, Ecnt, nrm, B[0], B[1]);
        k_gemv<<<gn, T, 0, stream>>>(B[1], B[2], B[1], nullptr, acc, W + 5 * FIN * NHID, bb, n, 2, 0);
        int sg = std::min(512, cdiv(n, 4));
        k_bnstats<<<sg, T, 0, stream>>>(acc, n, st);
    };

    // branch 1: full graph
    branch(x, N, ei, E, W1, b1, dis1, nrm1, B1, acc1, st1);
    // branch 2: cluster1 pooled graph
    k_scatter<<<cdiv(N * FIN, T), T, 0, stream>>>(x, cl1, N, xp1, cnt1);
    k_divcnt<<<cdiv(C1n * FIN, T), T, 0, stream>>>(xp1, cnt1, C1n);
    branch(xp1, C1n, eic1, E1, W2, b2, dis2, nrm2, B2, acc2, st2);
    k_bnrelu<<<cdiv(C1n * NHID, T), T, 0, stream>>>(acc2, C1n, st2, g2, bt2);
    // branch 3: cluster2 pooled graph
    k_scatter<<<cdiv(N * FIN, T), T, 0, stream>>>(x, cl2, N, xp2, cnt2);
    k_divcnt<<<cdiv(C2n * FIN, T), T, 0, stream>>>(xp2, cnt2, C2n);
    branch(xp2, C2n, eic2, E2, W3, b3, dis3, nrm3, B3, acc3, st3);
    k_bnrelu<<<cdiv(C2n * NHID, T), T, 0, stream>>>(acc3, C2n, st3, g3, bt3);
    // final fused mix
    k_final<<<cdiv(N, T), T, 0, stream>>>(acc1, st1, g1, bt1, acc2, cl1, acc3, cl2,
                                          x, Wm, bm, (float*)d_out, N);
}